// Round 5
// baseline (252.168 us; speedup 1.0000x reference)
//
#include <hip/hip_runtime.h>
#include <hip/hip_bf16.h>
#include <math.h>

// B=4, T=2048, C=1024, H=16, D=64, M = B*T = 8192

typedef short bf16x8 __attribute__((ext_vector_type(8)));
typedef float f32x4 __attribute__((ext_vector_type(4)));
typedef _Float16 f16x4 __attribute__((ext_vector_type(4)));

__device__ __forceinline__ short f2b(float f) {
    unsigned u = __float_as_uint(f);
    u = (u + 0x7fffu + ((u >> 16) & 1u)) >> 16;
    return (short)u;
}
__device__ __forceinline__ float b2f(short s) {
    return __uint_as_float(((unsigned)(unsigned short)s) << 16);
}

// ---------------------------------------------------------------- cast x
__global__ __launch_bounds__(256) void cast_x_kernel(const float* __restrict__ x,
                                                     short* __restrict__ xb, int n4) {
    int idx = blockIdx.x * 256 + threadIdx.x;
    if (idx >= n4) return;
    float4 v = ((const float4*)x)[idx];
    short4 o;
    o.x = f2b(v.x); o.y = f2b(v.y); o.z = f2b(v.z); o.w = f2b(v.w);
    ((short4*)xb)[idx] = o;
}

// ------------------------------------------- cast + transpose weights (fp32 [K][N] -> bf16 [N][K])
__global__ __launch_bounds__(256) void wtrans_kernel(const float* W0, const float* W1,
                                                     const float* W2, const float* W3,
                                                     short* O0, short* O1, short* O2, short* O3) {
    const float* W; short* O;
    switch (blockIdx.z) {
        case 0: W = W0; O = O0; break;
        case 1: W = W1; O = O1; break;
        case 2: W = W2; O = O2; break;
        default: W = W3; O = O3; break;
    }
    __shared__ __align__(16) float Ls[64 * 68];
    int tid = threadIdx.x;
    int n0 = blockIdx.x * 64, k0 = blockIdx.y * 64;
    #pragma unroll
    for (int it = 0; it < 4; ++it) {
        int c = tid + it * 256;
        int r = c >> 4, off = (c & 15) * 4;
        *(float4*)&Ls[r * 68 + off] = *(const float4*)&W[(k0 + r) * 1024 + n0 + off];
    }
    __syncthreads();
    #pragma unroll
    for (int it = 0; it < 2; ++it) {
        int c = tid + it * 256;
        int n = c >> 3, koff = (c & 7) * 8;
        union { short s[8]; int4 v; } u;
        #pragma unroll
        for (int k = 0; k < 8; ++k) u.s[k] = f2b(Ls[(koff + k) * 68 + n]);
        *(int4*)&O[(n0 + n) * 1024 + k0 + koff] = u.v;
    }
}

// ---------------------------------------------------------------- GEMM 256x256 (QKV), m201 8-phase port
// 8 waves (2M x 4N), per-wave output 128x64, BK=64, 4 phases/K-tile:
//  ph0: A(i0-3,kk0)x4 + B(kk0)x4 reads; ph1: A(i4-7,kk0)x4; ph2: A(i0-3,kk1)+B(kk1) x8; ph3: A(i4-7,kk1)x4.
// Each phase: {ds_read || 2 global_load_lds -> s_barrier -> lgkmcnt(0) -> setprio(1)
//              -> 16 MFMA -> setprio(0) -> s_barrier}. Overlap = cross-wave stagger at barrier.
// LDS 160 KiB: A triple-buffered (3x32KB, slot t%3; staged at t for t+2 -> 5-phase lead for
// HBM-streamed x), B double-buffered (2x32KB, slot t&1; staged at t for t+1 -> 3-phase lead,
// weights L2-resident). ONE counted vmcnt(4)/tile (FIFO drains A(t+1)+B(t+1), leaves A(t+2)).
// R5 FIX: sB must start at pB_w+64 (it increments at end of t=0 before first use at t=1);
// R4's +128 staged B(t+2) into B(t+1)'s slot -> wrong K-blocks from tile 2 on (absmax 5.0).
// T2 swizzle (bank conflicts 0): stored chunk c of row r holds logical chunk c^((r&8)?2:0);
// staging pre-swizzles the GLOBAL src col; reads XOR the same on quad.
__global__ __launch_bounds__(512, 2) void gemm256_kernel(const short* __restrict__ A,
                                                         const short* Bt0, const short* Bt1, const short* Bt2,
                                                         const float* b0, const float* b1, const float* b2,
                                                         float s0, float s1, float s2,
                                                         void* O0, void* O1, void* O2) {
    int z = blockIdx.z;
    const short* Bt   = (z == 0) ? Bt0 : (z == 1) ? Bt1 : Bt2;
    const float* bias = (z == 0) ? b0  : (z == 1) ? b1  : b2;
    float scl         = (z == 0) ? s0  : (z == 1) ? s1  : s2;
    void* Out         = (z == 0) ? O0  : (z == 1) ? O1  : O2;

    // A: 3 slots x 16384 shorts at 0; B: 2 slots x 16384 shorts at short-off 49152 (byte 98304)
    __shared__ __align__(16) short lds[81920];   // 160 KiB

    int tid = threadIdx.x;
    int w = tid >> 6, lane = tid & 63, quad = lane >> 4, l15 = lane & 15;
    int m0 = blockIdx.x * 256, n0 = blockIdx.y * 256;

    // staging: each instr covers 16 rows x 32 shorts (one kk-half), 4 lanes/row, pre-swizzled src col
    int srccol = ((lane & 3) * 8) ^ ((lane & 32) ? 16 : 0);
    const short* pA_w = A  + (m0 + (2 * w) * 16 + (lane >> 2)) * 1024 + srccol;
    const short* pB_w = Bt + (n0 + (2 * w) * 16 + (lane >> 2)) * 1024 + srccol;
    int dst_w = (2 * w) * 1024;   // short-offset of wave's row16-pair within a slot

    // read side
    int offR = l15 * 64 + ((quad * 16) ^ ((l15 & 8) << 2));  // byte off within 1024B subtile
    int ar0 = (w >> 2) * 8;   // A row16 base (0 or 8)
    int br0 = (w & 3) * 4;    // B row16 base
    const char* ldsb = (const char*)lds;

    f32x4 acc[8][4] = {};
    bf16x8 aF[4], bF[4];

#define STG(p, off) __builtin_amdgcn_global_load_lds( \
        (const __attribute__((address_space(1))) unsigned int*)(p), \
        (__attribute__((address_space(3))) unsigned int*)&lds[off], 16, 0, 0)
#define RDA(bb, r16, kk) (*(const bf16x8*)(ldsb + (bb) + ((r16) * 2 + (kk)) * 1024 + offR))
#define RDB(bb, r16, kk) (*(const bf16x8*)(ldsb + 98304 + (bb) + ((r16) * 2 + (kk)) * 1024 + offR))
#define PRE_MFMA do { __builtin_amdgcn_s_barrier(); \
        asm volatile("s_waitcnt lgkmcnt(0)" ::: "memory"); \
        __builtin_amdgcn_sched_barrier(0); \
        __builtin_amdgcn_s_setprio(1); } while (0)
#define POST_MFMA do { __builtin_amdgcn_s_setprio(0); \
        __builtin_amdgcn_s_barrier(); \
        __builtin_amdgcn_sched_barrier(0); } while (0)

    // ---- prologue: A(0)->slot0, B(0)->slot0, A(1)->slot1, B(1)->slot1 (queue order matters) ----
    STG(pA_w,                 dst_w);            STG(pA_w + 32,            dst_w + 512);
    STG(pA_w + 16384,         dst_w + 1024);     STG(pA_w + 16384 + 32,    dst_w + 1536);
    STG(pB_w,         49152 + dst_w);            STG(pB_w + 32,    49152 + dst_w + 512);
    STG(pB_w + 16384, 49152 + dst_w + 1024);     STG(pB_w + 16384 + 32, 49152 + dst_w + 1536);
    STG(pA_w + 64,            16384 + dst_w);        STG(pA_w + 96,            16384 + dst_w + 512);
    STG(pA_w + 16384 + 64,    16384 + dst_w + 1024); STG(pA_w + 16384 + 96,    16384 + dst_w + 1536);
    STG(pB_w + 64,    49152 + 16384 + dst_w);        STG(pB_w + 96,    49152 + 16384 + dst_w + 512);
    STG(pB_w + 16384 + 64, 49152 + 16384 + dst_w + 1024);
    STG(pB_w + 16384 + 96, 49152 + 16384 + dst_w + 1536);
    asm volatile("s_waitcnt vmcnt(8)" ::: "memory");   // A(0),B(0) landed; A(1),B(1) in flight
    __builtin_amdgcn_s_barrier();
    __builtin_amdgcn_sched_barrier(0);

    int aB0 = 0, aB1 = 32768, aB2 = 65536;   // A slot byte bases: tile t, t+1, t+2
    int bB0 = 0;                             // B slot byte base: tile t
    const short* sA = pA_w + 128;            // stage src for A(t+2), first used at t=0
    const short* sB = pB_w + 64;             // stage src for B(t+1): +=64 at end of t=0 -> B(2) at t=1

    #pragma unroll 1
    for (int t = 0; t < 16; ++t) {
        int bN = 49152 + ((bB0 ^ 32768) >> 1) + dst_w;   // short-off base, B(t+1) slot
        int aN = (aB2 >> 1) + dst_w;                      // short-off base, A(t+2) slot

        // ---------- ph0: A(i0-3,kk0) + B(kk0) ---------- (8 reads)
        #pragma unroll
        for (int i = 0; i < 4; ++i) aF[i] = RDA(aB0, ar0 + i, 0);
        #pragma unroll
        for (int j = 0; j < 4; ++j) bF[j] = RDB(bB0, br0 + j, 0);
        if (t >= 1 && t < 15) { STG(sB, bN); STG(sB + 32, bN + 512); }
        PRE_MFMA;
        #pragma unroll
        for (int i = 0; i < 4; ++i)
            #pragma unroll
            for (int j = 0; j < 4; ++j)
                acc[i][j] = __builtin_amdgcn_mfma_f32_16x16x32_bf16(aF[i], bF[j], acc[i][j], 0, 0, 0);
        POST_MFMA;

        // ---------- ph1: A(i4-7,kk0) ---------- (4 reads)
        #pragma unroll
        for (int i = 0; i < 4; ++i) aF[i] = RDA(aB0, ar0 + 4 + i, 0);
        if (t >= 1 && t < 15) { STG(sB + 16384, bN + 1024); STG(sB + 16384 + 32, bN + 1536); }
        PRE_MFMA;
        #pragma unroll
        for (int i = 0; i < 4; ++i)
            #pragma unroll
            for (int j = 0; j < 4; ++j)
                acc[4 + i][j] = __builtin_amdgcn_mfma_f32_16x16x32_bf16(aF[i], bF[j], acc[4 + i][j], 0, 0, 0);
        POST_MFMA;

        // ---------- ph2: A(i0-3,kk1) + B(kk1) ---------- (8 reads)
        #pragma unroll
        for (int i = 0; i < 4; ++i) aF[i] = RDA(aB0, ar0 + i, 1);
        #pragma unroll
        for (int j = 0; j < 4; ++j) bF[j] = RDB(bB0, br0 + j, 1);
        if (t < 14) { STG(sA, aN); STG(sA + 32, aN + 512); }
        PRE_MFMA;
        #pragma unroll
        for (int i = 0; i < 4; ++i)
            #pragma unroll
            for (int j = 0; j < 4; ++j)
                acc[i][j] = __builtin_amdgcn_mfma_f32_16x16x32_bf16(aF[i], bF[j], acc[i][j], 0, 0, 0);
        POST_MFMA;

        // ---------- ph3: A(i4-7,kk1) ---------- (4 reads)
        #pragma unroll
        for (int i = 0; i < 4; ++i) aF[i] = RDA(aB0, ar0 + 4 + i, 1);
        if (t < 14) { STG(sA + 16384, aN + 1024); STG(sA + 16384 + 32, aN + 1536); }
        __builtin_amdgcn_s_barrier();
        asm volatile("s_waitcnt lgkmcnt(0)" ::: "memory");
        __builtin_amdgcn_sched_barrier(0);
        __builtin_amdgcn_s_setprio(1);
        #pragma unroll
        for (int i = 0; i < 4; ++i)
            #pragma unroll
            for (int j = 0; j < 4; ++j)
                acc[4 + i][j] = __builtin_amdgcn_mfma_f32_16x16x32_bf16(aF[i], bF[j], acc[4 + i][j], 0, 0, 0);
        __builtin_amdgcn_s_setprio(0);
        if (t < 14) {
            asm volatile("s_waitcnt vmcnt(4)" ::: "memory");   // drain A(t+1)+B(t+1); A(t+2) flies
        } else if (t == 14) {
            asm volatile("s_waitcnt vmcnt(0)" ::: "memory");   // staging over: drain A(15),B(15)
        }
        if (t < 15) {
            __builtin_amdgcn_s_barrier();
            __builtin_amdgcn_sched_barrier(0);
        }

        int tmp = aB0; aB0 = aB1; aB1 = aB2; aB2 = tmp;
        bB0 ^= 32768;
        sA += 64; sB += 64;
    }
#undef STG
#undef RDA
#undef RDB
#undef PRE_MFMA
#undef POST_MFMA

    // ---- epilogue: wave tile 128x64 at (mrow, ncol) ----
    int mrow = m0 + (w >> 2) * 128;
    int ncol = n0 + (w & 3) * 64;
    #pragma unroll
    for (int i = 0; i < 8; ++i) {
        #pragma unroll
        for (int j = 0; j < 4; ++j) {
            int gn = ncol + j * 16 + l15;
            float bv = bias[gn];
            if (z == 2) {
                // V: f16 directly transposed [bh][d][t]; r-values consecutive t
                int gm0 = mrow + i * 16 + quad * 4;
                int b = gm0 >> 11, tt = gm0 & 2047, h = gn >> 6, d = gn & 63;
                f16x4 hv;
                #pragma unroll
                for (int r = 0; r < 4; ++r) hv[r] = (_Float16)((acc[i][j][r] + bv) * scl);
                *(f16x4*)&((_Float16*)Out)[((b * 16 + h) * 64 + d) * 2048 + tt] = hv;
            } else {
                #pragma unroll
                for (int r = 0; r < 4; ++r) {
                    int gm = mrow + i * 16 + quad * 4 + r;
                    float v = (acc[i][j][r] + bv) * scl;
                    int b = gm >> 11, tt = gm & 2047, h = gn >> 6, d = gn & 63;
                    ((short*)Out)[(((b * 16 + h) * 2048) + tt) * 64 + d] = f2b(v);
                }
            }
        }
    }
}

// ---------------------------------------------------------------- GEMM 128x256, BK=64 (R2 schedule; proj)
// kk-split balanced phases (8 ds_read + 16 indep MFMA each) with one-phase read-ahead
// (counted lgkmcnt(8)); triple-buffered staging with counted vmcnt(3); 2 barriers/tile.
template<int MODE>
__global__ __launch_bounds__(512, 2) void gemm8_kernel(const short* __restrict__ A,
                                                       const short* Bt0, const short* Bt1, const short* Bt2,
                                                       const float* b0, const float* b1, const float* b2,
                                                       float s0, float s1, float s2,
                                                       void* O0, void* O1, void* O2) {
    int z = blockIdx.z;
    const short* Bt   = (z == 0) ? Bt0 : (z == 1) ? Bt1 : Bt2;
    const float* bias = (z == 0) ? b0  : (z == 1) ? b1  : b2;
    float scl         = (z == 0) ? s0  : (z == 1) ? s1  : s2;
    void* Out         = (z == 0) ? O0  : (z == 1) ? O1  : O2;

    __shared__ __align__(16) short lds[73728];

    int tid = threadIdx.x;
    int w = tid >> 6, lane = tid & 63, quad = lane >> 4, l15 = lane & 15;
    int m0 = blockIdx.x * 128, n0 = blockIdx.y * 256;

    int srccol = ((lane & 3) * 8) ^ ((lane & 32) ? 16 : 0);
    const short* pA0 = A  + (m0 + w * 16 + (lane >> 2)) * 1024 + srccol;
    const short* pA1 = pA0 + 32;
    const short* pB0 = Bt + (n0 + (2 * w) * 16 + (lane >> 2)) * 1024 + srccol;
    const short* pB1 = pB0 + 32;
    const short* pB2 = pB0 + 16 * 1024;
    const short* pB3 = pB2 + 32;

    int dA = (w * 2) * 512;
    int dB = 24576 + (w * 4) * 512;

    int offR = l15 * 64 + ((quad * 16) ^ ((l15 & 8) << 2));
    int ma4 = (w >> 2) * 4;
    int nb2 = (w & 3) * 2;
    int jrow0 = nb2, jrow1 = nb2 + 1, jrow2 = nb2 + 8, jrow3 = nb2 + 9;
    const char* ldsb = (const char*)lds;

    f32x4 acc[4][4] = {};
    bf16x8 afA[4], bfA[4], afB[4], bfB[4];

#define STG(p, off) __builtin_amdgcn_global_load_lds( \
        (const __attribute__((address_space(1))) unsigned int*)(p), \
        (__attribute__((address_space(3))) unsigned int*)&lds[off], 16, 0, 0)
#define RD(base, row, kk) (*(const bf16x8*)(ldsb + (base) + ((row) * 2 + (kk)) * 1024 + offR))

    STG(pA0,      dA);                 STG(pA1,      dA + 512);
    STG(pB0,      dB);                 STG(pB1,      dB + 512);
    STG(pB2,      dB + 1024);          STG(pB3,      dB + 1536);
    STG(pA0 + 64, 8192 + dA);          STG(pA1 + 64, 8192 + dA + 512);
    STG(pB0 + 64, 16384 + dB);         STG(pB1 + 64, 16384 + dB + 512);
    STG(pB2 + 64, 16384 + dB + 1024);  STG(pB3 + 64, 16384 + dB + 1536);
    asm volatile("s_waitcnt vmcnt(6)" ::: "memory");
    __builtin_amdgcn_s_barrier();
    __builtin_amdgcn_sched_barrier(0);

    #pragma unroll
    for (int i = 0; i < 4; ++i) afA[i] = RD(0, ma4 + i, 0);
    bfA[0] = RD(49152, jrow0, 0); bfA[1] = RD(49152, jrow1, 0);
    bfA[2] = RD(49152, jrow2, 0); bfA[3] = RD(49152, jrow3, 0);

    #pragma unroll
    for (int t = 0; t < 16; ++t) {
        const int rs  = t % 3;
        const int rs1 = (t + 1) % 3;
        const int ss  = (t + 2) % 3;
        const int Ar  = rs * 16384;
        const int Br  = 49152 + rs * 32768;
        const int Ar1 = rs1 * 16384;
        const int Br1 = 49152 + rs1 * 32768;

        #pragma unroll
        for (int i = 0; i < 4; ++i) afB[i] = RD(Ar, ma4 + i, 1);
        bfB[0] = RD(Br, jrow0, 1); bfB[1] = RD(Br, jrow1, 1);
        bfB[2] = RD(Br, jrow2, 1); bfB[3] = RD(Br, jrow3, 1);
        if (t + 2 < 16) {
            STG(pA0 + (t + 2) * 64, ss * 8192 + dA);
            STG(pA1 + (t + 2) * 64, ss * 8192 + dA + 512);
            STG(pB0 + (t + 2) * 64, ss * 16384 + dB);
        }
        asm volatile("s_waitcnt lgkmcnt(8)" ::: "memory");
        __builtin_amdgcn_sched_barrier(0);
        __builtin_amdgcn_s_setprio(1);
        #pragma unroll
        for (int i = 0; i < 4; ++i)
            #pragma unroll
            for (int j = 0; j < 4; ++j)
                acc[i][j] = __builtin_amdgcn_mfma_f32_16x16x32_bf16(afA[i], bfA[j], acc[i][j], 0, 0, 0);
        __builtin_amdgcn_s_setprio(0);
        if (t < 14) {
            asm volatile("s_waitcnt vmcnt(3)" ::: "memory");
        } else if (t == 14) {
            asm volatile("s_waitcnt vmcnt(0)" ::: "memory");
        }
        __builtin_amdgcn_s_barrier();
        __builtin_amdgcn_sched_barrier(0);

        if (t < 15) {
            #pragma unroll
            for (int i = 0; i < 4; ++i) afA[i] = RD(Ar1, ma4 + i, 0);
            bfA[0] = RD(Br1, jrow0, 0); bfA[1] = RD(Br1, jrow1, 0);
            bfA[2] = RD(Br1, jrow2, 0); bfA[3] = RD(Br1, jrow3, 0);
        }
        if (t + 2 < 16) {
            STG(pB1 + (t + 2) * 64, ss * 16384 + dB + 512);
            STG(pB2 + (t + 2) * 64, ss * 16384 + dB + 1024);
            STG(pB3 + (t + 2) * 64, ss * 16384 + dB + 1536);
        }
        if (t < 15) {
            asm volatile("s_waitcnt lgkmcnt(8)" ::: "memory");
        } else {
            asm volatile("s_waitcnt lgkmcnt(0)" ::: "memory");
        }
        __builtin_amdgcn_sched_barrier(0);
        __builtin_amdgcn_s_setprio(1);
        #pragma unroll
        for (int i = 0; i < 4; ++i)
            #pragma unroll
            for (int j = 0; j < 4; ++j)
                acc[i][j] = __builtin_amdgcn_mfma_f32_16x16x32_bf16(afB[i], bfB[j], acc[i][j], 0, 0, 0);
        __builtin_amdgcn_s_setprio(0);
        if (t < 15) {
            __builtin_amdgcn_s_barrier();
            __builtin_amdgcn_sched_barrier(0);
        }
    }
#undef STG
#undef RD

    int mrow = m0 + (w >> 2) * 64;
    int ncol = n0 + (w & 3) * 32;
    #pragma unroll
    for (int i = 0; i < 4; ++i) {
        #pragma unroll
        for (int j = 0; j < 4; ++j) {
            int gn = ncol + (j >> 1) * 128 + (j & 1) * 16 + l15;
            float bv = bias[gn];
            #pragma unroll
            for (int r = 0; r < 4; ++r) {
                int gm = mrow + i * 16 + quad * 4 + r;
                float v = (acc[i][j][r] + bv) * scl;
                if (MODE == 0) {
                    int b = gm >> 11, tt = gm & 2047, h = gn >> 6, d = gn & 63;
                    ((short*)Out)[(((b * 16 + h) * 2048) + tt) * 64 + d] = f2b(v);
                } else {
                    ((float*)Out)[gm * 1024 + gn] = v;
                }
            }
        }
    }
}

// ---------------------------------------------------------------- flash attention
// Q,K bf16 [bh][t][d] (Q pre-scaled by log2(e)/8); Vt f16 [bh][d][t]; Y bf16 [b*T+t][C]
__global__ __launch_bounds__(256, 3) void attn_kernel(const short* __restrict__ Q,
                                                      const short* __restrict__ K,
                                                      const _Float16* __restrict__ Vt,
                                                      short* __restrict__ Y) {
    __shared__ __align__(16) short    Ks[128 * 64];   // 16384 B, swizzled
    __shared__ __align__(16) _Float16 Vs[64 * 128];   // 16384 B, swizzled

    int tid = threadIdx.x;
    int w = tid >> 6, lane = tid & 63, quad = lane >> 4, l15 = lane & 15;
    int idx = blockIdx.x;
    int qi = 15 - (idx >> 6);   // longest blocks first
    int bh = idx & 63;

    const short* Qh = Q + bh * 2048 * 64;
    const short* Kh = K + bh * 2048 * 64;
    const _Float16* Vh = Vt + bh * 64 * 2048;

    bf16x8 qf[2][2];
    #pragma unroll
    for (int i = 0; i < 2; ++i)
        #pragma unroll
        for (int kh = 0; kh < 2; ++kh) {
            int t = qi * 128 + w * 32 + i * 16 + l15;
            qf[i][kh] = *(const bf16x8*)&Qh[t * 64 + kh * 32 + quad * 8];
        }

    int krow = lane >> 3;
    int kchunk = ((lane & 7) ^ krow) * 8;
    int vrow = lane >> 4;
    int vchunk = ((lane & 15) ^ (w * 4 + vrow)) * 8;

    int t7 = l15 & 7;
    int kf0_off = ((quad ^ t7) * 8);
    int kf1_off = (((quad + 4) ^ t7) * 8);
    int vsub = (quad & 1) * 4;
    int vchi = quad >> 1;

    f32x4 o[2][4] = {};
    float lsum[2] = {0.f, 0.f};

    for (int si = 0; si <= qi; ++si) {
        const short* Kt = Kh + si * 128 * 64;
        const _Float16* Vtile = Vh + si * 128;
        bool diag = (si == qi);

        __syncthreads();
        #pragma unroll
        for (int it = 0; it < 4; ++it) {
            int kr0 = it * 32 + w * 8;
            __builtin_amdgcn_global_load_lds(
                (const __attribute__((address_space(1))) unsigned int*)&Kt[(kr0 + krow) * 64 + kchunk],
                (__attribute__((address_space(3))) unsigned int*)&Ks[kr0 * 64], 16, 0, 0);
            int vr0 = it * 16 + w * 4;
            __builtin_amdgcn_global_load_lds(
                (const __attribute__((address_space(1))) unsigned int*)&Vtile[(vr0 + vrow) * 2048 + vchunk],
                (__attribute__((address_space(3))) unsigned int*)&Vs[vr0 * 128], 16, 0, 0);
        }
        __syncthreads();

        #pragma unroll
        for (int j = 0; j < 8; ++j) {
            int trow = (j * 16 + l15) * 64;
            bf16x8 kf0 = *(const bf16x8*)&Ks[trow + kf0_off];
            bf16x8 kf1 = *(const bf16x8*)&Ks[trow + kf1_off];
            f16x4 pfv[2];
            #pragma unroll
            for (int i = 0; i < 2; ++i) {
                f32x4 a = {};
                a = __builtin_amdgcn_mfma_f32_16x16x32_bf16(kf0, qf[i][0], a, 0, 0, 0);
                a = __builtin_amdgcn_mfma_f32_16x16x32_bf16(kf1, qf[i][1], a, 0, 0, 0);
                if (diag) {
                    int qrel = w * 32 + i * 16 + l15;
                    #pragma unroll
                    for (int r = 0; r < 4; ++r)
                        if (j * 16 + quad * 4 + r > qrel) a[r] = -1e30f;
                }
                float p0 = __builtin_amdgcn_exp2f(a[0]);
                float p1 = __builtin_amdgcn_exp2f(a[1]);
                float p2 = __builtin_amdgcn_exp2f(a[2]);
                float p3 = __builtin_amdgcn_exp2f(a[3]);
                lsum[i] += (p0 + p1) + (p2 + p3);
                pfv[i][0] = (_Float16)p0;
                pfv[i][1] = (_Float16)p1;
                pfv[i][2] = (_Float16)p2;
                pfv[i][3] = (_Float16)p3;
            }
            int vc = (j * 2 + vchi);
            #pragma unroll
            for (int mt = 0; mt < 4; ++mt) {
                int d = mt * 16 + l15;
                f16x4 vf = *(const f16x4*)&Vs[d * 128 + ((vc ^ l15) * 8) + vsub];
                o[0][mt] = __builtin_amdgcn_mfma_f32_16x16x16f16(vf, pfv[0], o[0][mt], 0, 0, 0);
                o[1][mt] = __builtin_amdgcn_mfma_f32_16x16x16f16(vf, pfv[1], o[1][mt], 0, 0, 0);
            }
        }
    }

    int b = bh >> 4, h = bh & 15;
    #pragma unroll
    for (int i = 0; i < 2; ++i) {
        float l = lsum[i];
        l += __shfl_xor(l, 16);
        l += __shfl_xor(l, 32);
        float rinv = 1.0f / l;
        int q = qi * 128 + w * 32 + i * 16 + l15;
        short* yrow = &Y[(b * 2048 + q) * 1024 + h * 64];
        #pragma unroll
        for (int mt = 0; mt < 4; ++mt) {
            short4 s4;
            s4.x = f2b(o[i][mt][0] * rinv);
            s4.y = f2b(o[i][mt][1] * rinv);
            s4.z = f2b(o[i][mt][2] * rinv);
            s4.w = f2b(o[i][mt][3] * rinv);
            *(short4*)&yrow[mt * 16 + quad * 4] = s4;
        }
    }
}

// ----------------------------------------------------------------
extern "C" void kernel_launch(void* const* d_in, const int* in_sizes, int n_in,
                              void* d_out, int out_size, void* d_ws, size_t ws_size,
                              hipStream_t stream) {
    const float* x  = (const float*)d_in[0];
    const float* Wk = (const float*)d_in[1];
    const float* bk = (const float*)d_in[2];
    const float* Wq = (const float*)d_in[3];
    const float* bq = (const float*)d_in[4];
    const float* Wv = (const float*)d_in[5];
    const float* bv = (const float*)d_in[6];
    const float* Wp = (const float*)d_in[7];
    const float* bp = (const float*)d_in[8];

    char* ws = (char*)d_ws;
    short*     xb  = (short*)(ws + 0);          // 16 MB  x bf16 [8192][1024]
    short*     Wqt = (short*)(ws + 16777216);   // 2 MB each, bf16 [N][K]
    short*     Wkt = (short*)(ws + 18874368);
    short*     Wvt = (short*)(ws + 20971520);
    short*     Wpt = (short*)(ws + 23068672);
    short*     Qb  = (short*)(ws + 25165824);   // 16 MB [B,H,T,D] (pre-scaled by log2e/8)
    short*     Kb  = (short*)(ws + 41943040);   // 16 MB [B,H,T,D]
    _Float16*  Vtb = (_Float16*)(ws + 75497472);// 16 MB [B,H,D,T] f16 (written directly by gemm z=2)
    short*     Yb  = (short*)(ws + 92274688);   // 16 MB [B*T][C]

    cast_x_kernel<<<8192, 256, 0, stream>>>(x, xb, 2097152);
    wtrans_kernel<<<dim3(16, 16, 4), 256, 0, stream>>>(Wq, Wk, Wv, Wp, Wqt, Wkt, Wvt, Wpt);
    gemm256_kernel<<<dim3(32, 4, 3), 512, 0, stream>>>(xb, Wqt, Wkt, Wvt, bq, bk, bv,
                                                       0.18033688011112042f /* log2e/8 */, 1.0f, 1.0f,
                                                       (void*)Qb, (void*)Kb, (void*)Vtb);
    attn_kernel<<<1024, 256, 0, stream>>>(Qb, Kb, Vtb, Yb);
    gemm8_kernel<1><<<dim3(64, 4, 1), 512, 0, stream>>>(Yb, Wpt, nullptr, nullptr,
                                                        bp, nullptr, nullptr,
                                                        1.0f, 1.0f, 1.0f,
                                                        (void*)d_out, nullptr, nullptr);
}

// Round 6
// 236.654 us; speedup vs baseline: 1.0656x; 1.0656x over previous
//
#include <hip/hip_runtime.h>
#include <hip/hip_bf16.h>
#include <math.h>

// B=4, T=2048, C=1024, H=16, D=64, M = B*T = 8192

typedef short bf16x8 __attribute__((ext_vector_type(8)));
typedef float f32x4 __attribute__((ext_vector_type(4)));
typedef _Float16 f16x4 __attribute__((ext_vector_type(4)));

__device__ __forceinline__ short f2b(float f) {
    unsigned u = __float_as_uint(f);
    u = (u + 0x7fffu + ((u >> 16) & 1u)) >> 16;
    return (short)u;
}
__device__ __forceinline__ float b2f(short s) {
    return __uint_as_float(((unsigned)(unsigned short)s) << 16);
}

// ---------------------------------------------------------------- prep: cast x (blocks 0..8191)
//                                       + cast/transpose 4 weight mats (blocks 8192..9215)
__global__ __launch_bounds__(256) void prep_kernel(const float* __restrict__ x, short* __restrict__ xb,
                                                   const float* W0, const float* W1,
                                                   const float* W2, const float* W3,
                                                   short* O0, short* O1, short* O2, short* O3) {
    int tid = threadIdx.x;
    if (blockIdx.x < 8192) {
        int idx = blockIdx.x * 256 + tid;
        float4 v = ((const float4*)x)[idx];
        short4 o;
        o.x = f2b(v.x); o.y = f2b(v.y); o.z = f2b(v.z); o.w = f2b(v.w);
        ((short4*)xb)[idx] = o;
        return;
    }
    int wid = blockIdx.x - 8192;         // 0..1023
    const float* W; short* O;
    switch (wid >> 8) {
        case 0: W = W0; O = O0; break;
        case 1: W = W1; O = O1; break;
        case 2: W = W2; O = O2; break;
        default: W = W3; O = O3; break;
    }
    int rem = wid & 255;
    int n0 = (rem >> 4) * 64, k0 = (rem & 15) * 64;
    __shared__ __align__(16) float Ls[64 * 68];
    #pragma unroll
    for (int it = 0; it < 4; ++it) {
        int c = tid + it * 256;
        int r = c >> 4, off = (c & 15) * 4;
        *(float4*)&Ls[r * 68 + off] = *(const float4*)&W[(k0 + r) * 1024 + n0 + off];
    }
    __syncthreads();
    #pragma unroll
    for (int it = 0; it < 2; ++it) {
        int c = tid + it * 256;
        int n = c >> 3, koff = (c & 7) * 8;
        union { short s[8]; int4 v; } u;
        #pragma unroll
        for (int k = 0; k < 8; ++k) u.s[k] = f2b(Ls[(koff + k) * 68 + n]);
        *(int4*)&O[(n0 + n) * 1024 + k0 + koff] = u.v;
    }
}

// ---------------------------------------------------------------- GEMM 128x256, BK=64 (R2 schedule)
// kk-split balanced phases (8 ds_read + 16 indep MFMA each) with one-phase read-ahead
// (counted lgkmcnt(8)); triple-buffered staging with counted vmcnt(3); 2 barriers/tile.
// T2 st_16x32 swizzle via pre-swizzled global src col (bank conflicts = 0).
// MODE==0 && z==2 (V): epilogue writes f16 DIRECTLY TRANSPOSED to [bh][d][t] (no vtrans kernel).
template<int MODE>
__global__ __launch_bounds__(512, 2) void gemm8_kernel(const short* __restrict__ A,
                                                       const short* Bt0, const short* Bt1, const short* Bt2,
                                                       const float* b0, const float* b1, const float* b2,
                                                       float s0, float s1, float s2,
                                                       void* O0, void* O1, void* O2) {
    int z = blockIdx.z;
    const short* Bt   = (z == 0) ? Bt0 : (z == 1) ? Bt1 : Bt2;
    const float* bias = (z == 0) ? b0  : (z == 1) ? b1  : b2;
    float scl         = (z == 0) ? s0  : (z == 1) ? s1  : s2;
    void* Out         = (z == 0) ? O0  : (z == 1) ? O1  : O2;

    __shared__ __align__(16) short lds[73728];

    int tid = threadIdx.x;
    int w = tid >> 6, lane = tid & 63, quad = lane >> 4, l15 = lane & 15;
    int m0 = blockIdx.x * 128, n0 = blockIdx.y * 256;

    int srccol = ((lane & 3) * 8) ^ ((lane & 32) ? 16 : 0);
    const short* pA0 = A  + (m0 + w * 16 + (lane >> 2)) * 1024 + srccol;
    const short* pA1 = pA0 + 32;
    const short* pB0 = Bt + (n0 + (2 * w) * 16 + (lane >> 2)) * 1024 + srccol;
    const short* pB1 = pB0 + 32;
    const short* pB2 = pB0 + 16 * 1024;
    const short* pB3 = pB2 + 32;

    int dA = (w * 2) * 512;
    int dB = 24576 + (w * 4) * 512;

    int offR = l15 * 64 + ((quad * 16) ^ ((l15 & 8) << 2));
    int ma4 = (w >> 2) * 4;
    int nb2 = (w & 3) * 2;
    int jrow0 = nb2, jrow1 = nb2 + 1, jrow2 = nb2 + 8, jrow3 = nb2 + 9;
    const char* ldsb = (const char*)lds;

    f32x4 acc[4][4] = {};
    bf16x8 afA[4], bfA[4], afB[4], bfB[4];

#define STG(p, off) __builtin_amdgcn_global_load_lds( \
        (const __attribute__((address_space(1))) unsigned int*)(p), \
        (__attribute__((address_space(3))) unsigned int*)&lds[off], 16, 0, 0)
#define RD(base, row, kk) (*(const bf16x8*)(ldsb + (base) + ((row) * 2 + (kk)) * 1024 + offR))

    STG(pA0,      dA);                 STG(pA1,      dA + 512);
    STG(pB0,      dB);                 STG(pB1,      dB + 512);
    STG(pB2,      dB + 1024);          STG(pB3,      dB + 1536);
    STG(pA0 + 64, 8192 + dA);          STG(pA1 + 64, 8192 + dA + 512);
    STG(pB0 + 64, 16384 + dB);         STG(pB1 + 64, 16384 + dB + 512);
    STG(pB2 + 64, 16384 + dB + 1024);  STG(pB3 + 64, 16384 + dB + 1536);
    asm volatile("s_waitcnt vmcnt(6)" ::: "memory");
    __builtin_amdgcn_s_barrier();
    __builtin_amdgcn_sched_barrier(0);

    #pragma unroll
    for (int i = 0; i < 4; ++i) afA[i] = RD(0, ma4 + i, 0);
    bfA[0] = RD(49152, jrow0, 0); bfA[1] = RD(49152, jrow1, 0);
    bfA[2] = RD(49152, jrow2, 0); bfA[3] = RD(49152, jrow3, 0);

    #pragma unroll
    for (int t = 0; t < 16; ++t) {
        const int rs  = t % 3;
        const int rs1 = (t + 1) % 3;
        const int ss  = (t + 2) % 3;
        const int Ar  = rs * 16384;
        const int Br  = 49152 + rs * 32768;
        const int Ar1 = rs1 * 16384;
        const int Br1 = 49152 + rs1 * 32768;

        #pragma unroll
        for (int i = 0; i < 4; ++i) afB[i] = RD(Ar, ma4 + i, 1);
        bfB[0] = RD(Br, jrow0, 1); bfB[1] = RD(Br, jrow1, 1);
        bfB[2] = RD(Br, jrow2, 1); bfB[3] = RD(Br, jrow3, 1);
        if (t + 2 < 16) {
            STG(pA0 + (t + 2) * 64, ss * 8192 + dA);
            STG(pA1 + (t + 2) * 64, ss * 8192 + dA + 512);
            STG(pB0 + (t + 2) * 64, ss * 16384 + dB);
        }
        asm volatile("s_waitcnt lgkmcnt(8)" ::: "memory");
        __builtin_amdgcn_sched_barrier(0);
        __builtin_amdgcn_s_setprio(1);
        #pragma unroll
        for (int i = 0; i < 4; ++i)
            #pragma unroll
            for (int j = 0; j < 4; ++j)
                acc[i][j] = __builtin_amdgcn_mfma_f32_16x16x32_bf16(afA[i], bfA[j], acc[i][j], 0, 0, 0);
        __builtin_amdgcn_s_setprio(0);
        if (t < 14) {
            asm volatile("s_waitcnt vmcnt(3)" ::: "memory");
        } else if (t == 14) {
            asm volatile("s_waitcnt vmcnt(0)" ::: "memory");
        }
        __builtin_amdgcn_s_barrier();
        __builtin_amdgcn_sched_barrier(0);

        if (t < 15) {
            #pragma unroll
            for (int i = 0; i < 4; ++i) afA[i] = RD(Ar1, ma4 + i, 0);
            bfA[0] = RD(Br1, jrow0, 0); bfA[1] = RD(Br1, jrow1, 0);
            bfA[2] = RD(Br1, jrow2, 0); bfA[3] = RD(Br1, jrow3, 0);
        }
        if (t + 2 < 16) {
            STG(pB1 + (t + 2) * 64, ss * 16384 + dB + 512);
            STG(pB2 + (t + 2) * 64, ss * 16384 + dB + 1024);
            STG(pB3 + (t + 2) * 64, ss * 16384 + dB + 1536);
        }
        if (t < 15) {
            asm volatile("s_waitcnt lgkmcnt(8)" ::: "memory");
        } else {
            asm volatile("s_waitcnt lgkmcnt(0)" ::: "memory");
        }
        __builtin_amdgcn_sched_barrier(0);
        __builtin_amdgcn_s_setprio(1);
        #pragma unroll
        for (int i = 0; i < 4; ++i)
            #pragma unroll
            for (int j = 0; j < 4; ++j)
                acc[i][j] = __builtin_amdgcn_mfma_f32_16x16x32_bf16(afB[i], bfB[j], acc[i][j], 0, 0, 0);
        __builtin_amdgcn_s_setprio(0);
        if (t < 15) {
            __builtin_amdgcn_s_barrier();
            __builtin_amdgcn_sched_barrier(0);
        }
    }
#undef STG
#undef RD

    int mrow = m0 + (w >> 2) * 64;
    int ncol = n0 + (w & 3) * 32;
    #pragma unroll
    for (int i = 0; i < 4; ++i) {
        #pragma unroll
        for (int j = 0; j < 4; ++j) {
            int gn = ncol + (j >> 1) * 128 + (j & 1) * 16 + l15;
            float bv = bias[gn];
            if (MODE == 0 && z == 2) {
                // V: write f16 directly transposed [bh][d][t]; r-values are consecutive t
                int gm0 = mrow + i * 16 + quad * 4;
                int b = gm0 >> 11, tt = gm0 & 2047, h = gn >> 6, d = gn & 63;
                f16x4 hv;
                #pragma unroll
                for (int r = 0; r < 4; ++r) hv[r] = (_Float16)((acc[i][j][r] + bv) * scl);
                *(f16x4*)&((_Float16*)Out)[((b * 16 + h) * 64 + d) * 2048 + tt] = hv;
            } else {
                #pragma unroll
                for (int r = 0; r < 4; ++r) {
                    int gm = mrow + i * 16 + quad * 4 + r;
                    float v = (acc[i][j][r] + bv) * scl;
                    if (MODE == 0) {
                        int b = gm >> 11, tt = gm & 2047, h = gn >> 6, d = gn & 63;
                        ((short*)Out)[(((b * 16 + h) * 2048) + tt) * 64 + d] = f2b(v);
                    } else {
                        ((float*)Out)[gm * 1024 + gn] = v;
                    }
                }
            }
        }
    }
}

// ---------------------------------------------------------------- flash attention
// Q,K bf16 [bh][t][d] (Q pre-scaled by log2(e)/8); Vt f16 [bh][d][t]; Y bf16 [b*T+t][C]
// S^T = K Q^T: C col=l15=q, row=quad*4+r=s -> per-lane softmax, no shuffles.
// p = exp2(s) packed f16 IS the 16x16x16f16 B-fragment -> PV directly from registers.
// K and V^T tiles staged via async global_load_lds into XOR-swizzled unpadded LDS.
__global__ __launch_bounds__(256, 3) void attn_kernel(const short* __restrict__ Q,
                                                      const short* __restrict__ K,
                                                      const _Float16* __restrict__ Vt,
                                                      short* __restrict__ Y) {
    __shared__ __align__(16) short    Ks[128 * 64];   // 16384 B, swizzled
    __shared__ __align__(16) _Float16 Vs[64 * 128];   // 16384 B, swizzled

    int tid = threadIdx.x;
    int w = tid >> 6, lane = tid & 63, quad = lane >> 4, l15 = lane & 15;
    int idx = blockIdx.x;
    int qi = 15 - (idx >> 6);   // longest blocks first
    int bh = idx & 63;

    const short* Qh = Q + bh * 2048 * 64;
    const short* Kh = K + bh * 2048 * 64;
    const _Float16* Vh = Vt + bh * 64 * 2048;

    bf16x8 qf[2][2];
    #pragma unroll
    for (int i = 0; i < 2; ++i)
        #pragma unroll
        for (int kh = 0; kh < 2; ++kh) {
            int t = qi * 128 + w * 32 + i * 16 + l15;
            qf[i][kh] = *(const bf16x8*)&Qh[t * 64 + kh * 32 + quad * 8];
        }

    int krow = lane >> 3;
    int kchunk = ((lane & 7) ^ krow) * 8;
    int vrow = lane >> 4;
    int vchunk = ((lane & 15) ^ (w * 4 + vrow)) * 8;

    int t7 = l15 & 7;
    int kf0_off = ((quad ^ t7) * 8);
    int kf1_off = (((quad + 4) ^ t7) * 8);
    int vsub = (quad & 1) * 4;
    int vchi = quad >> 1;

    f32x4 o[2][4] = {};
    float lsum[2] = {0.f, 0.f};

    for (int si = 0; si <= qi; ++si) {
        const short* Kt = Kh + si * 128 * 64;
        const _Float16* Vtile = Vh + si * 128;
        bool diag = (si == qi);

        __syncthreads();
        #pragma unroll
        for (int it = 0; it < 4; ++it) {
            int kr0 = it * 32 + w * 8;
            __builtin_amdgcn_global_load_lds(
                (const __attribute__((address_space(1))) unsigned int*)&Kt[(kr0 + krow) * 64 + kchunk],
                (__attribute__((address_space(3))) unsigned int*)&Ks[kr0 * 64], 16, 0, 0);
            int vr0 = it * 16 + w * 4;
            __builtin_amdgcn_global_load_lds(
                (const __attribute__((address_space(1))) unsigned int*)&Vtile[(vr0 + vrow) * 2048 + vchunk],
                (__attribute__((address_space(3))) unsigned int*)&Vs[vr0 * 128], 16, 0, 0);
        }
        __syncthreads();

        #pragma unroll
        for (int j = 0; j < 8; ++j) {
            int trow = (j * 16 + l15) * 64;
            bf16x8 kf0 = *(const bf16x8*)&Ks[trow + kf0_off];
            bf16x8 kf1 = *(const bf16x8*)&Ks[trow + kf1_off];
            f16x4 pfv[2];
            #pragma unroll
            for (int i = 0; i < 2; ++i) {
                f32x4 a = {};
                a = __builtin_amdgcn_mfma_f32_16x16x32_bf16(kf0, qf[i][0], a, 0, 0, 0);
                a = __builtin_amdgcn_mfma_f32_16x16x32_bf16(kf1, qf[i][1], a, 0, 0, 0);
                if (diag) {
                    int qrel = w * 32 + i * 16 + l15;
                    #pragma unroll
                    for (int r = 0; r < 4; ++r)
                        if (j * 16 + quad * 4 + r > qrel) a[r] = -1e30f;
                }
                float p0 = __builtin_amdgcn_exp2f(a[0]);
                float p1 = __builtin_amdgcn_exp2f(a[1]);
                float p2 = __builtin_amdgcn_exp2f(a[2]);
                float p3 = __builtin_amdgcn_exp2f(a[3]);
                lsum[i] += (p0 + p1) + (p2 + p3);
                pfv[i][0] = (_Float16)p0;
                pfv[i][1] = (_Float16)p1;
                pfv[i][2] = (_Float16)p2;
                pfv[i][3] = (_Float16)p3;
            }
            int vc = (j * 2 + vchi);
            #pragma unroll
            for (int mt = 0; mt < 4; ++mt) {
                int d = mt * 16 + l15;
                f16x4 vf = *(const f16x4*)&Vs[d * 128 + ((vc ^ l15) * 8) + vsub];
                o[0][mt] = __builtin_amdgcn_mfma_f32_16x16x16f16(vf, pfv[0], o[0][mt], 0, 0, 0);
                o[1][mt] = __builtin_amdgcn_mfma_f32_16x16x16f16(vf, pfv[1], o[1][mt], 0, 0, 0);
            }
        }
    }

    int b = bh >> 4, h = bh & 15;
    #pragma unroll
    for (int i = 0; i < 2; ++i) {
        float l = lsum[i];
        l += __shfl_xor(l, 16);
        l += __shfl_xor(l, 32);
        float rinv = 1.0f / l;
        int q = qi * 128 + w * 32 + i * 16 + l15;
        short* yrow = &Y[(b * 2048 + q) * 1024 + h * 64];
        #pragma unroll
        for (int mt = 0; mt < 4; ++mt) {
            short4 s4;
            s4.x = f2b(o[i][mt][0] * rinv);
            s4.y = f2b(o[i][mt][1] * rinv);
            s4.z = f2b(o[i][mt][2] * rinv);
            s4.w = f2b(o[i][mt][3] * rinv);
            *(short4*)&yrow[mt * 16 + quad * 4] = s4;
        }
    }
}

// ----------------------------------------------------------------
extern "C" void kernel_launch(void* const* d_in, const int* in_sizes, int n_in,
                              void* d_out, int out_size, void* d_ws, size_t ws_size,
                              hipStream_t stream) {
    const float* x  = (const float*)d_in[0];
    const float* Wk = (const float*)d_in[1];
    const float* bk = (const float*)d_in[2];
    const float* Wq = (const float*)d_in[3];
    const float* bq = (const float*)d_in[4];
    const float* Wv = (const float*)d_in[5];
    const float* bv = (const float*)d_in[6];
    const float* Wp = (const float*)d_in[7];
    const float* bp = (const float*)d_in[8];

    char* ws = (char*)d_ws;
    short*     xb  = (short*)(ws + 0);          // 16 MB  x bf16 [8192][1024]
    short*     Wqt = (short*)(ws + 16777216);   // 2 MB each, bf16 [N][K]
    short*     Wkt = (short*)(ws + 18874368);
    short*     Wvt = (short*)(ws + 20971520);
    short*     Wpt = (short*)(ws + 23068672);
    short*     Qb  = (short*)(ws + 25165824);   // 16 MB [B,H,T,D] (pre-scaled by log2e/8)
    short*     Kb  = (short*)(ws + 41943040);   // 16 MB [B,H,T,D]
    _Float16*  Vtb = (_Float16*)(ws + 75497472);// 16 MB [B,H,D,T] f16 (written directly by gemm z=2)
    short*     Yb  = (short*)(ws + 92274688);   // 16 MB [B*T][C]

    prep_kernel<<<9216, 256, 0, stream>>>(x, xb, Wq, Wk, Wv, Wp, Wqt, Wkt, Wvt, Wpt);
    gemm8_kernel<0><<<dim3(64, 4, 3), 512, 0, stream>>>(xb, Wqt, Wkt, Wvt, bq, bk, bv,
                                                        0.18033688011112042f /* log2e/8 */, 1.0f, 1.0f,
                                                        (void*)Qb, (void*)Kb, (void*)Vtb);
    attn_kernel<<<1024, 256, 0, stream>>>(Qb, Kb, Vtb, Yb);
    gemm8_kernel<1><<<dim3(64, 4, 1), 512, 0, stream>>>(Yb, Wpt, nullptr, nullptr,
                                                        bp, nullptr, nullptr,
                                                        1.0f, 1.0f, 1.0f,
                                                        (void*)d_out, nullptr, nullptr);
}